// Round 17
// baseline (194.293 us; speedup 1.0000x reference)
//
#include <hip/hip_runtime.h>

#define NN 50000
#define NN_PAD 50016  // grid-covered row pad (guard-free GEMM stores)
#define NE 600000
#define DD 128
#define NH 4
#define RB_CNT 3125   // NN/16 (exact)
#define RB_PAD 3128

#define SCAN_T 512
#define SCAN_B ((NN + SCAN_T - 1) / SCAN_T)

#define LOG2E 1.44269504088896340736f

typedef short s16x8 __attribute__((ext_vector_type(8)));
typedef float f32x4 __attribute__((ext_vector_type(4)));

// fp32 -> bf16 (RNE) and back
__device__ __forceinline__ unsigned short bfh(float f) {
  unsigned u = __float_as_uint(f);
  return (unsigned short)((u + 0x7fffu + ((u >> 16) & 1u)) >> 16);
}
__device__ __forceinline__ float bff(unsigned short h) {
  return __uint_as_float(((unsigned)h) << 16);
}

// cross-lane add via DPP. 0xB1 quad xor1, 0x4E quad xor2, 0x141 row_half_mirror,
// 0x124/0x128 row_ror:4/:8.
template <int CTRL>
__device__ __forceinline__ float dpp_add(float x) {
  int y = __builtin_amdgcn_update_dpp(0, __float_as_int(x), CTRL, 0xf, 0xf, true);
  return x + __int_as_float(y);
}

// ---------- CSR build ----------
// grid-parallel zero (hipMemsetAsync graph-captures to a ~42us 1-block fill!)
__global__ void zero_deg(int* __restrict__ deg) {
  int i = (blockIdx.x * 256 + threadIdx.x) << 2;
  if (i < NN) {
    int4 z = make_int4(0, 0, 0, 0);
    if (i + 3 < NN) *(int4*)(deg + i) = z;
    else for (int k = i; k < NN; k++) deg[k] = 0;
  }
}

__global__ void count_deg(const int* __restrict__ ei, int* __restrict__ deg) {
  int e = blockIdx.x * 256 + threadIdx.x;
  if (e < NE) atomicAdd(deg + ei[NE + e], 1);
}

__global__ __launch_bounds__(SCAN_T) void scan_partial(
    const int* __restrict__ deg, int* __restrict__ rowp, int* __restrict__ bsum) {
  __shared__ int buf[SCAN_T];
  int b = blockIdx.x, t = threadIdx.x;
  int i = b * SCAN_T + t;
  int v = (i < NN) ? deg[i] : 0;
  buf[t] = v;
  __syncthreads();
  for (int o = 1; o < SCAN_T; o <<= 1) {
    int add = (t >= o) ? buf[t - o] : 0;
    __syncthreads();
    buf[t] += add;
    __syncthreads();
  }
  if (i < NN) rowp[i] = buf[t] - v;
  if (t == SCAN_T - 1) bsum[b] = buf[t];
}

// fused: block-sum scan (redundant per block) + rowp finalize + cur seed
__global__ __launch_bounds__(SCAN_T) void scan_finish(
    const int* __restrict__ bsum, int* __restrict__ rowp, int* __restrict__ cur) {
  __shared__ int sb[SCAN_T];
  int b = blockIdx.x, t = threadIdx.x;
  int v = (t < SCAN_B) ? bsum[t] : 0;
  sb[t] = v;
  __syncthreads();
  for (int o = 1; o < SCAN_T; o <<= 1) {
    int add = (t >= o) ? sb[t - o] : 0;
    __syncthreads();
    sb[t] += add;
    __syncthreads();
  }
  int boff = sb[b] - bsum[b];          // exclusive prefix at this block (b < SCAN_B)
  int i = b * SCAN_T + t;
  if (i < NN) {
    int r = rowp[i] + boff;
    rowp[i] = r;
    cur[i] = r;
  }
  if (b == 0 && t == 0) rowp[NN] = sb[SCAN_B - 1];   // total == NE
}

// store src * 256 (bf16 row byte-stride); cur holds absolute positions
__global__ void scatter_src(const int* __restrict__ ei,
                            int* __restrict__ cur, int* __restrict__ colsrc) {
  int e = blockIdx.x * 256 + threadIdx.x;
  if (e < NE) {
    int d = ei[NE + e];
    int p = atomicAdd(cur + d, 1);
    colsrc[p] = ei[e] << 8;
  }
}

// ---------- prep (one dispatch): A fragments + both layers' W fragments ----------
__global__ __launch_bounds__(256) void prep_all(
    const float* __restrict__ h,
    const float* __restrict__ Wl0, const float* __restrict__ Wr0,
    const float* __restrict__ Wl1, const float* __restrict__ Wr1,
    unsigned short* __restrict__ Ah, unsigned short* __restrict__ Am,
    unsigned short* __restrict__ Bh, unsigned short* __restrict__ Bm) {
  int b = blockIdx.x;
  if (b < RB_CNT) {
    int tid = b * 256 + threadIdx.x;
    int lr = tid & 15;
    int g = (tid >> 4) & 3;
    int kt = (tid >> 6) & 3;
    int rb = tid >> 8;
    int row = rb * 16 + lr;
    const float* p = h + (size_t)row * DD + kt * 32 + 4 * g;
    float4 f0 = *(const float4*)(p);
    float4 f1 = *(const float4*)(p + 16);
    float fs[8] = {f0.x, f0.y, f0.z, f0.w, f1.x, f1.y, f1.z, f1.w};
    s16x8 hi, mid;
#pragma unroll
    for (int e = 0; e < 8; e++) {
      unsigned short hh = bfh(fs[e]);
      hi[e] = (short)hh;
      mid[e] = (short)bfh(fs[e] - bff(hh));
    }
    *(s16x8*)(Ah + (size_t)tid * 8) = hi;
    *(s16x8*)(Am + (size_t)tid * 8) = mid;
  } else {
    int tid = (b - RB_CNT) * 256 + threadIdx.x;   // 0..8191
    int lay = tid >> 12;
    int t = tid & 4095;
    int lr = t & 15;
    int g = (t >> 4) & 3;
    int kt = (t >> 6) & 3;
    int ct = t >> 8;
    int col = ct * 16 + lr;
    const float* W = (col < DD) ? (lay ? Wl1 : Wl0) : (lay ? Wr1 : Wr0);
    int cc = (col < DD) ? col : col - DD;
    s16x8 hi, mid;
#pragma unroll
    for (int e = 0; e < 8; e++) {
      int k = kt * 32 + ((e >> 2) << 4) + 4 * g + (e & 3);
      float w = W[(size_t)k * DD + cc];
      unsigned short hh = bfh(w);
      hi[e] = (short)hh;
      mid[e] = (short)bfh(w - bff(hh));
    }
    *(s16x8*)(Bh + (size_t)tid * 8) = hi;
    *(s16x8*)(Bm + (size_t)tid * 8) = mid;
  }
}

// ---------- dual GEMM: split-bf16 MFMA; 3 waves/SIMD for latency hiding ----------
__global__ __launch_bounds__(256, 3) void dual_gemm_mfma(
    const unsigned short* __restrict__ Ah, const unsigned short* __restrict__ Am,
    const unsigned short* __restrict__ Bh, const unsigned short* __restrict__ Bm,
    const float* __restrict__ blv, const float* __restrict__ brv,
    unsigned short* __restrict__ xlb, unsigned short* __restrict__ xrb) {
  const int tid = threadIdx.x;
  const int lane = tid & 63;
  const int wv = tid >> 6;
  const int lr = lane & 15;
  const int g = lane >> 4;
  const int rb0 = blockIdx.x * 2;

  f32x4 acc[2][4];
#pragma unroll
  for (int rt = 0; rt < 2; rt++)
#pragma unroll
    for (int nt = 0; nt < 4; nt++)
#pragma unroll
      for (int e = 0; e < 4; e++) acc[rt][nt][e] = 0.f;

#pragma unroll
  for (int kt = 0; kt < 4; kt++) {
    s16x8 ah[2], am[2], bh[4], bm[4];
#pragma unroll
    for (int rt = 0; rt < 2; rt++) {
      size_t off = ((((size_t)((rb0 + rt) * 4 + kt)) * 4 + g) * 16 + lr) * 8;
      ah[rt] = *(const s16x8*)(Ah + off);
      am[rt] = *(const s16x8*)(Am + off);
    }
#pragma unroll
    for (int nt = 0; nt < 4; nt++) {
      int ct = wv * 4 + nt;
      size_t off = ((((size_t)(ct * 4 + kt)) * 4 + g) * 16 + lr) * 8;
      bh[nt] = *(const s16x8*)(Bh + off);
      bm[nt] = *(const s16x8*)(Bm + off);
    }
#pragma unroll
    for (int rt = 0; rt < 2; rt++)
#pragma unroll
      for (int nt = 0; nt < 4; nt++) {
        acc[rt][nt] = __builtin_amdgcn_mfma_f32_16x16x32_bf16(ah[rt], bh[nt], acc[rt][nt], 0, 0, 0);
        acc[rt][nt] = __builtin_amdgcn_mfma_f32_16x16x32_bf16(ah[rt], bm[nt], acc[rt][nt], 0, 0, 0);
        acc[rt][nt] = __builtin_amdgcn_mfma_f32_16x16x32_bf16(am[rt], bh[nt], acc[rt][nt], 0, 0, 0);
      }
  }

#pragma unroll
  for (int nt = 0; nt < 4; nt++) {
    int col = wv * 64 + nt * 16 + lr;
    unsigned short* dst = (col < DD) ? (xlb + col) : (xrb + (col - DD));
    float bv = (col < DD) ? blv[col] : brv[col - DD];
#pragma unroll
    for (int rt = 0; rt < 2; rt++) {
      int rowb = blockIdx.x * 32 + rt * 16 + 4 * g;
#pragma unroll
      for (int r = 0; r < 4; r++)
        dst[(size_t)(rowb + r) * DD] = bfh(acc[rt][nt][r] + bv);   // rows < NN_PAD
    }
  }
}

// ---------- fused edge path v6: half-wave per node, 4-edge chunks ----------
template <int SPLIT>
__global__ __launch_bounds__(256) void fused_edge_agg(
    const int* __restrict__ rowp, const int* __restrict__ colsrc,
    const unsigned short* __restrict__ xlb, const unsigned short* __restrict__ xrb,
    const float* __restrict__ att, const float* __restrict__ bias,
    const float* __restrict__ gam, const float* __restrict__ bet,
    float* __restrict__ out, unsigned short* __restrict__ Oh,
    unsigned short* __restrict__ Om) {
  int node = (blockIdx.x * 256 + threadIdx.x) >> 5;   // half-wave id
  if (node >= NN) return;
  int il = threadIdx.x & 31;
  int d0 = il << 2;                       // 4 dims per lane; head = il>>3

  ushort4 xru = *(const ushort4*)(xrb + (size_t)node * DD + d0);
  float4 xrv; xrv.x = bff(xru.x); xrv.y = bff(xru.y);
  xrv.z = bff(xru.z); xrv.w = bff(xru.w);
  float4 atv = *(const float4*)(att + d0);
  atv.x *= LOG2E; atv.y *= LOG2E; atv.z *= LOG2E; atv.w *= LOG2E;
  int j0 = rowp[node];
  int j1 = rowp[node + 1];

  float den = 0.f;
  float a0 = 0.f, a1 = 0.f, a2 = 0.f, a3 = 0.f;
  const char* xlb8 = (const char*)xlb;
  const int goff = il << 3;               // 8B per lane within row

  for (int j = j0; j < j1; j += 4) {
    bool v1 = (j + 1) < j1, v2 = (j + 2) < j1, v3 = (j + 3) < j1;
    int s0 = colsrc[j];                   // pre-scaled by 256
    int s1 = colsrc[v1 ? j + 1 : j];
    int s2 = colsrc[v2 ? j + 2 : j];
    int s3 = colsrc[v3 ? j + 3 : j];
    ushort4 g0 = *(const ushort4*)(xlb8 + (size_t)(unsigned)(s0 + goff));
    ushort4 g1 = *(const ushort4*)(xlb8 + (size_t)(unsigned)(s1 + goff));
    ushort4 g2 = *(const ushort4*)(xlb8 + (size_t)(unsigned)(s2 + goff));
    ushort4 g3 = *(const ushort4*)(xlb8 + (size_t)(unsigned)(s3 + goff));
    float x00 = bff(g0.x), x01 = bff(g0.y), x02 = bff(g0.z), x03 = bff(g0.w);
    float x10 = bff(g1.x), x11 = bff(g1.y), x12 = bff(g1.z), x13 = bff(g1.w);
    float x20 = bff(g2.x), x21 = bff(g2.y), x22 = bff(g2.z), x23 = bff(g2.w);
    float x30 = bff(g3.x), x31 = bff(g3.y), x32 = bff(g3.z), x33 = bff(g3.w);

    float t0, t1, t2, t3;
    t0 = x00 + xrv.x; t1 = x01 + xrv.y; t2 = x02 + xrv.z; t3 = x03 + xrv.w;
    t0 = fmaxf(t0, 0.2f * t0); t1 = fmaxf(t1, 0.2f * t1);
    t2 = fmaxf(t2, 0.2f * t2); t3 = fmaxf(t3, 0.2f * t3);
    float p0 = (t0 * atv.x + t1 * atv.y) + (t2 * atv.z + t3 * atv.w);
    t0 = x10 + xrv.x; t1 = x11 + xrv.y; t2 = x12 + xrv.z; t3 = x13 + xrv.w;
    t0 = fmaxf(t0, 0.2f * t0); t1 = fmaxf(t1, 0.2f * t1);
    t2 = fmaxf(t2, 0.2f * t2); t3 = fmaxf(t3, 0.2f * t3);
    float p1 = (t0 * atv.x + t1 * atv.y) + (t2 * atv.z + t3 * atv.w);
    t0 = x20 + xrv.x; t1 = x21 + xrv.y; t2 = x22 + xrv.z; t3 = x23 + xrv.w;
    t0 = fmaxf(t0, 0.2f * t0); t1 = fmaxf(t1, 0.2f * t1);
    t2 = fmaxf(t2, 0.2f * t2); t3 = fmaxf(t3, 0.2f * t3);
    float p2 = (t0 * atv.x + t1 * atv.y) + (t2 * atv.z + t3 * atv.w);
    t0 = x30 + xrv.x; t1 = x31 + xrv.y; t2 = x32 + xrv.z; t3 = x33 + xrv.w;
    t0 = fmaxf(t0, 0.2f * t0); t1 = fmaxf(t1, 0.2f * t1);
    t2 = fmaxf(t2, 0.2f * t2); t3 = fmaxf(t3, 0.2f * t3);
    float p3 = (t0 * atv.x + t1 * atv.y) + (t2 * atv.z + t3 * atv.w);

    // 8-lane (per-head) reduces — 4 independent chains pipeline in the VALU
    p0 = dpp_add<0xB1>(p0);  p1 = dpp_add<0xB1>(p1);
    p2 = dpp_add<0xB1>(p2);  p3 = dpp_add<0xB1>(p3);
    p0 = dpp_add<0x4E>(p0);  p1 = dpp_add<0x4E>(p1);
    p2 = dpp_add<0x4E>(p2);  p3 = dpp_add<0x4E>(p3);
    p0 = dpp_add<0x141>(p0); p1 = dpp_add<0x141>(p1);
    p2 = dpp_add<0x141>(p2); p3 = dpp_add<0x141>(p3);

    float w0 = exp2f(p0);
    float w1 = v1 ? exp2f(p1) : 0.f;
    float w2 = v2 ? exp2f(p2) : 0.f;
    float w3 = v3 ? exp2f(p3) : 0.f;
    den += (w0 + w1) + (w2 + w3);
    a0 += (w0 * x00 + w1 * x10) + (w2 * x20 + w3 * x30);
    a1 += (w0 * x01 + w1 * x11) + (w2 * x21 + w3 * x31);
    a2 += (w0 * x02 + w1 * x12) + (w2 * x22 + w3 * x32);
    a3 += (w0 * x03 + w1 * x13) + (w2 * x23 + w3 * x33);
  }

  float inv = 1.f / (den + 1e-16f);
  float4 bi = *(const float4*)(bias + d0);
  float vx0 = a0 * inv + bi.x, vx1 = a1 * inv + bi.y;
  float vx2 = a2 * inv + bi.z, vx3 = a3 * inv + bi.w;

  // LayerNorm over 128 dims within the 32-lane half
  float s1 = (vx0 + vx1) + (vx2 + vx3);
  float s2 = (vx0 * vx0 + vx1 * vx1) + (vx2 * vx2 + vx3 * vx3);
  s1 = dpp_add<0xB1>(s1);  s2 = dpp_add<0xB1>(s2);
  s1 = dpp_add<0x4E>(s1);  s2 = dpp_add<0x4E>(s2);
  s1 = dpp_add<0x124>(s1); s2 = dpp_add<0x124>(s2);
  s1 = dpp_add<0x128>(s1); s2 = dpp_add<0x128>(s2);
  s1 += __shfl_xor(s1, 16); s2 += __shfl_xor(s2, 16);
  float mean = s1 * (1.f / 128.f);
  float var = s2 * (1.f / 128.f) - mean * mean;
  float rstd = rsqrtf(var + 1e-5f);
  float4 gm = *(const float4*)(gam + d0);
  float4 bt = *(const float4*)(bet + d0);
  float n0 = (vx0 - mean) * rstd * gm.x + bt.x;
  float n1 = (vx1 - mean) * rstd * gm.y + bt.y;
  float n2 = (vx2 - mean) * rstd * gm.z + bt.z;
  float n3 = (vx3 - mean) * rstd * gm.w + bt.w;
  n0 = n0 > 0.f ? n0 : expf(n0) - 1.f;
  n1 = n1 > 0.f ? n1 : expf(n1) - 1.f;
  n2 = n2 > 0.f ? n2 : expf(n2) - 1.f;
  n3 = n3 > 0.f ? n3 : expf(n3) - 1.f;

  if (SPLIT) {
    int rb = node >> 4, lr16 = node & 15;
    int kt = d0 >> 5;
    int g = (d0 & 15) >> 2;
    int e0 = ((d0 >> 4) & 1) << 2;
    size_t off = ((((size_t)(rb * 4 + kt)) * 4 + g) * 16 + lr16) * 8 + e0;
    unsigned short h0 = bfh(n0), h1 = bfh(n1), h2 = bfh(n2), h3 = bfh(n3);
    ushort4 hv; hv.x = h0; hv.y = h1; hv.z = h2; hv.w = h3;
    ushort4 mv;
    mv.x = bfh(n0 - bff(h0)); mv.y = bfh(n1 - bff(h1));
    mv.z = bfh(n2 - bff(h2)); mv.w = bfh(n3 - bff(h3));
    *(ushort4*)(Oh + off) = hv;
    *(ushort4*)(Om + off) = mv;
  } else {
    float4 o; o.x = n0; o.y = n1; o.z = n2; o.w = n3;
    *(float4*)(out + (size_t)node * DD + d0) = o;
  }
}

extern "C" void kernel_launch(void* const* d_in, const int* in_sizes, int n_in,
                              void* d_out, int out_size, void* d_ws, size_t ws_size,
                              hipStream_t stream) {
  const float* x  = (const float*)d_in[0];
  const int*   ei = (const int*)d_in[1];
  const float* Wl[2]   = {(const float*)d_in[2],  (const float*)d_in[10]};
  const float* bl[2]   = {(const float*)d_in[3],  (const float*)d_in[11]};
  const float* Wr[2]   = {(const float*)d_in[4],  (const float*)d_in[12]};
  const float* br[2]   = {(const float*)d_in[5],  (const float*)d_in[13]};
  const float* att[2]  = {(const float*)d_in[6],  (const float*)d_in[14]};
  const float* bias[2] = {(const float*)d_in[7],  (const float*)d_in[15]};
  const float* gam[2]  = {(const float*)d_in[8],  (const float*)d_in[16]};
  const float* bet[2]  = {(const float*)d_in[9],  (const float*)d_in[17]};
  float* out = (float*)d_out;

  char* w = (char*)d_ws;
  auto carve = [&](size_t bytes) {
    char* p = w;
    w += (bytes + 255) & ~(size_t)255;
    return p;
  };
  unsigned short* xlb = (unsigned short*)carve((size_t)NN_PAD * DD * 2);
  unsigned short* xrb = (unsigned short*)carve((size_t)NN_PAD * DD * 2);
  int*   deg    = (int*)carve((size_t)NN * 4);
  int*   cur    = (int*)carve((size_t)NN * 4);
  int*   rowp   = (int*)carve((size_t)(NN + 1) * 4);
  int*   colsrc = (int*)carve((size_t)NE * 4);
  int*   bsum   = (int*)carve((size_t)SCAN_B * 4);
  unsigned short* Ah = (unsigned short*)carve((size_t)RB_PAD * 2048 * 2);
  unsigned short* Am = (unsigned short*)carve((size_t)RB_PAD * 2048 * 2);
  unsigned short* Bh = (unsigned short*)carve((size_t)8192 * 8 * 2);
  unsigned short* Bm = (unsigned short*)carve((size_t)8192 * 8 * 2);

  // CSR build (recomputed every call — deterministic, no cross-call state)
  zero_deg<<<(NN / 4 + 255) / 256, 256, 0, stream>>>(deg);
  count_deg<<<(NE + 255) / 256, 256, 0, stream>>>(ei, deg);
  scan_partial<<<SCAN_B, SCAN_T, 0, stream>>>(deg, rowp, bsum);
  scan_finish<<<SCAN_B, SCAN_T, 0, stream>>>(bsum, rowp, cur);
  scatter_src<<<(NE + 255) / 256, 256, 0, stream>>>(ei, cur, colsrc);

  // layer-0 A split + both layers' W split, one dispatch
  prep_all<<<RB_CNT + 32, 256, 0, stream>>>(x, Wl[0], Wr[0], Wl[1], Wr[1],
                                            Ah, Am, Bh, Bm);

  for (int l = 0; l < 2; l++) {
    dual_gemm_mfma<<<(NN + 31) / 32, 256, 0, stream>>>(
        Ah, Am, Bh + (size_t)l * 4096 * 8, Bm + (size_t)l * 4096 * 8,
        bl[l], br[l], xlb, xrb);
    if (l == 0) {
      fused_edge_agg<1><<<(NN * 32 + 255) / 256, 256, 0, stream>>>(
          rowp, colsrc, xlb, xrb, att[l], bias[l], gam[l], bet[l], out, Ah, Am);
    } else {
      fused_edge_agg<0><<<(NN * 32 + 255) / 256, 256, 0, stream>>>(
          rowp, colsrc, xlb, xrb, att[l], bias[l], gam[l], bet[l], out, Ah, Am);
    }
  }
}

// Round 18
// 183.874 us; speedup vs baseline: 1.0567x; 1.0567x over previous
//
#include <hip/hip_runtime.h>

#define NN 50000
#define NN_PAD 50016  // grid-covered row pad (guard-free GEMM stores)
#define NE 600000
#define DD 128
#define NH 4
#define RB_CNT 3125   // NN/16 (exact)
#define RB_PAD 3128
#define GEMM_BLKS ((NN + 31) / 32)          // 1563
#define COUNT_BLKS ((NE + 255) / 256)       // 2344
#define ZERO_BLKS ((NN / 4 + 255) / 256)    // 49

#define SCAN_T 512
#define SCAN_B ((NN + SCAN_T - 1) / SCAN_T)

#define LOG2E 1.44269504088896340736f

typedef short s16x8 __attribute__((ext_vector_type(8)));
typedef float f32x4 __attribute__((ext_vector_type(4)));

// fp32 -> bf16 (RNE) and back
__device__ __forceinline__ unsigned short bfh(float f) {
  unsigned u = __float_as_uint(f);
  return (unsigned short)((u + 0x7fffu + ((u >> 16) & 1u)) >> 16);
}
__device__ __forceinline__ float bff(unsigned short h) {
  return __uint_as_float(((unsigned)h) << 16);
}

// cross-lane add via DPP. 0xB1 quad xor1, 0x4E quad xor2, 0x141 row_half_mirror,
// 0x124/0x128 row_ror:4/:8.
template <int CTRL>
__device__ __forceinline__ float dpp_add(float x) {
  int y = __builtin_amdgcn_update_dpp(0, __float_as_int(x), CTRL, 0xf, 0xf, true);
  return x + __int_as_float(y);
}

// ---------- device bodies (shared by fused dispatches) ----------
__device__ __forceinline__ void prep_a_body(
    int tid, const float* __restrict__ h,
    unsigned short* __restrict__ Ah, unsigned short* __restrict__ Am) {
  int lr = tid & 15;
  int g = (tid >> 4) & 3;
  int kt = (tid >> 6) & 3;
  int rb = tid >> 8;
  int row = rb * 16 + lr;
  const float* p = h + (size_t)row * DD + kt * 32 + 4 * g;
  float4 f0 = *(const float4*)(p);
  float4 f1 = *(const float4*)(p + 16);
  float fs[8] = {f0.x, f0.y, f0.z, f0.w, f1.x, f1.y, f1.z, f1.w};
  s16x8 hi, mid;
#pragma unroll
  for (int e = 0; e < 8; e++) {
    unsigned short hh = bfh(fs[e]);
    hi[e] = (short)hh;
    mid[e] = (short)bfh(fs[e] - bff(hh));
  }
  *(s16x8*)(Ah + (size_t)tid * 8) = hi;
  *(s16x8*)(Am + (size_t)tid * 8) = mid;
}

__device__ __forceinline__ void prep_w_body(
    int tid, const float* __restrict__ Wl0, const float* __restrict__ Wr0,
    const float* __restrict__ Wl1, const float* __restrict__ Wr1,
    unsigned short* __restrict__ Bh, unsigned short* __restrict__ Bm) {
  int lay = tid >> 12;
  int t = tid & 4095;
  int lr = t & 15;
  int g = (t >> 4) & 3;
  int kt = (t >> 6) & 3;
  int ct = t >> 8;
  int col = ct * 16 + lr;
  const float* W = (col < DD) ? (lay ? Wl1 : Wl0) : (lay ? Wr1 : Wr0);
  int cc = (col < DD) ? col : col - DD;
  s16x8 hi, mid;
#pragma unroll
  for (int e = 0; e < 8; e++) {
    int k = kt * 32 + ((e >> 2) << 4) + 4 * g + (e & 3);
    float w = W[(size_t)k * DD + cc];
    unsigned short hh = bfh(w);
    hi[e] = (short)hh;
    mid[e] = (short)bfh(w - bff(hh));
  }
  *(s16x8*)(Bh + (size_t)tid * 8) = hi;
  *(s16x8*)(Bm + (size_t)tid * 8) = mid;
}

__device__ __forceinline__ void gemm_body(
    int bid, int tid,
    const unsigned short* __restrict__ Ah, const unsigned short* __restrict__ Am,
    const unsigned short* __restrict__ Bh, const unsigned short* __restrict__ Bm,
    const float* __restrict__ blv, const float* __restrict__ brv,
    unsigned short* __restrict__ xlb, unsigned short* __restrict__ xrb) {
  const int lane = tid & 63;
  const int wv = tid >> 6;
  const int lr = lane & 15;
  const int g = lane >> 4;
  const int rb0 = bid * 2;

  f32x4 acc[2][4];
#pragma unroll
  for (int rt = 0; rt < 2; rt++)
#pragma unroll
    for (int nt = 0; nt < 4; nt++)
#pragma unroll
      for (int e = 0; e < 4; e++) acc[rt][nt][e] = 0.f;

#pragma unroll
  for (int kt = 0; kt < 4; kt++) {
    s16x8 ah[2], am[2], bh[4], bm[4];
#pragma unroll
    for (int rt = 0; rt < 2; rt++) {
      size_t off = ((((size_t)((rb0 + rt) * 4 + kt)) * 4 + g) * 16 + lr) * 8;
      ah[rt] = *(const s16x8*)(Ah + off);
      am[rt] = *(const s16x8*)(Am + off);
    }
#pragma unroll
    for (int nt = 0; nt < 4; nt++) {
      int ct = wv * 4 + nt;
      size_t off = ((((size_t)(ct * 4 + kt)) * 4 + g) * 16 + lr) * 8;
      bh[nt] = *(const s16x8*)(Bh + off);
      bm[nt] = *(const s16x8*)(Bm + off);
    }
#pragma unroll
    for (int rt = 0; rt < 2; rt++)
#pragma unroll
      for (int nt = 0; nt < 4; nt++) {
        acc[rt][nt] = __builtin_amdgcn_mfma_f32_16x16x32_bf16(ah[rt], bh[nt], acc[rt][nt], 0, 0, 0);
        acc[rt][nt] = __builtin_amdgcn_mfma_f32_16x16x32_bf16(ah[rt], bm[nt], acc[rt][nt], 0, 0, 0);
        acc[rt][nt] = __builtin_amdgcn_mfma_f32_16x16x32_bf16(am[rt], bh[nt], acc[rt][nt], 0, 0, 0);
      }
  }

#pragma unroll
  for (int nt = 0; nt < 4; nt++) {
    int col = wv * 64 + nt * 16 + lr;
    unsigned short* dst = (col < DD) ? (xlb + col) : (xrb + (col - DD));
    float bv = (col < DD) ? blv[col] : brv[col - DD];
#pragma unroll
    for (int rt = 0; rt < 2; rt++) {
      int rowb = bid * 32 + rt * 16 + 4 * g;
#pragma unroll
      for (int r = 0; r < 4; r++)
        dst[(size_t)(rowb + r) * DD] = bfh(acc[rt][nt][r] + bv);   // rows < NN_PAD
    }
  }
}

// ---------- dispatch 1: prep_all ∥ zero_deg ----------
__global__ __launch_bounds__(256) void init_fused(
    const float* __restrict__ h,
    const float* __restrict__ Wl0, const float* __restrict__ Wr0,
    const float* __restrict__ Wl1, const float* __restrict__ Wr1,
    unsigned short* __restrict__ Ah, unsigned short* __restrict__ Am,
    unsigned short* __restrict__ Bh, unsigned short* __restrict__ Bm,
    int* __restrict__ deg) {
  int b = blockIdx.x;
  if (b < RB_CNT) {
    prep_a_body(b * 256 + threadIdx.x, h, Ah, Am);
  } else if (b < RB_CNT + 32) {
    prep_w_body((b - RB_CNT) * 256 + threadIdx.x, Wl0, Wr0, Wl1, Wr1, Bh, Bm);
  } else {
    int i = ((b - RB_CNT - 32) * 256 + threadIdx.x) << 2;
    if (i < NN) {
      if (i + 3 < NN) *(int4*)(deg + i) = make_int4(0, 0, 0, 0);
      else for (int k = i; k < NN; k++) deg[k] = 0;
    }
  }
}

// ---------- dispatch 2: GEMM layer 0 ∥ count_deg ----------
__global__ __launch_bounds__(256, 3) void count_gemm_fused(
    const unsigned short* __restrict__ Ah, const unsigned short* __restrict__ Am,
    const unsigned short* __restrict__ Bh, const unsigned short* __restrict__ Bm,
    const float* __restrict__ blv, const float* __restrict__ brv,
    unsigned short* __restrict__ xlb, unsigned short* __restrict__ xrb,
    const int* __restrict__ ei, int* __restrict__ deg) {
  int b = blockIdx.x;
  if (b < GEMM_BLKS) {
    gemm_body(b, threadIdx.x, Ah, Am, Bh, Bm, blv, brv, xlb, xrb);
  } else {
    int e = (b - GEMM_BLKS) * 256 + threadIdx.x;
    if (e < NE) atomicAdd(deg + ei[NE + e], 1);
  }
}

// ---------- plain GEMM (layer 1) ----------
__global__ __launch_bounds__(256, 3) void dual_gemm_mfma(
    const unsigned short* __restrict__ Ah, const unsigned short* __restrict__ Am,
    const unsigned short* __restrict__ Bh, const unsigned short* __restrict__ Bm,
    const float* __restrict__ blv, const float* __restrict__ brv,
    unsigned short* __restrict__ xlb, unsigned short* __restrict__ xrb) {
  gemm_body(blockIdx.x, threadIdx.x, Ah, Am, Bh, Bm, blv, brv, xlb, xrb);
}

// ---------- CSR scans ----------
__global__ __launch_bounds__(SCAN_T) void scan_partial(
    const int* __restrict__ deg, int* __restrict__ rowp, int* __restrict__ bsum) {
  __shared__ int buf[SCAN_T];
  int b = blockIdx.x, t = threadIdx.x;
  int i = b * SCAN_T + t;
  int v = (i < NN) ? deg[i] : 0;
  buf[t] = v;
  __syncthreads();
  for (int o = 1; o < SCAN_T; o <<= 1) {
    int add = (t >= o) ? buf[t - o] : 0;
    __syncthreads();
    buf[t] += add;
    __syncthreads();
  }
  if (i < NN) rowp[i] = buf[t] - v;
  if (t == SCAN_T - 1) bsum[b] = buf[t];
}

__global__ __launch_bounds__(SCAN_T) void scan_finish(
    const int* __restrict__ bsum, int* __restrict__ rowp, int* __restrict__ cur) {
  __shared__ int sb[SCAN_T];
  int b = blockIdx.x, t = threadIdx.x;
  int v = (t < SCAN_B) ? bsum[t] : 0;
  sb[t] = v;
  __syncthreads();
  for (int o = 1; o < SCAN_T; o <<= 1) {
    int add = (t >= o) ? sb[t - o] : 0;
    __syncthreads();
    sb[t] += add;
    __syncthreads();
  }
  int boff = sb[b] - bsum[b];
  int i = b * SCAN_T + t;
  if (i < NN) {
    int r = rowp[i] + boff;
    rowp[i] = r;
    cur[i] = r;
  }
  if (b == 0 && t == 0) rowp[NN] = sb[SCAN_B - 1];
}

__global__ void scatter_src(const int* __restrict__ ei,
                            int* __restrict__ cur, int* __restrict__ colsrc) {
  int e = blockIdx.x * 256 + threadIdx.x;
  if (e < NE) {
    int d = ei[NE + e];
    int p = atomicAdd(cur + d, 1);
    colsrc[p] = ei[e] << 8;
  }
}

// ---------- fused edge path v7: half-wave per node, 4-edge chunks,
//            colsrc software prefetch (collapse 2-level load chain) ----------
template <int SPLIT>
__global__ __launch_bounds__(256) void fused_edge_agg(
    const int* __restrict__ rowp, const int* __restrict__ colsrc,
    const unsigned short* __restrict__ xlb, const unsigned short* __restrict__ xrb,
    const float* __restrict__ att, const float* __restrict__ bias,
    const float* __restrict__ gam, const float* __restrict__ bet,
    float* __restrict__ out, unsigned short* __restrict__ Oh,
    unsigned short* __restrict__ Om) {
  int node = (blockIdx.x * 256 + threadIdx.x) >> 5;   // half-wave id
  if (node >= NN) return;
  int il = threadIdx.x & 31;
  int d0 = il << 2;                       // 4 dims per lane; head = il>>3

  ushort4 xru = *(const ushort4*)(xrb + (size_t)node * DD + d0);
  float4 xrv; xrv.x = bff(xru.x); xrv.y = bff(xru.y);
  xrv.z = bff(xru.z); xrv.w = bff(xru.w);
  float4 atv = *(const float4*)(att + d0);
  atv.x *= LOG2E; atv.y *= LOG2E; atv.z *= LOG2E; atv.w *= LOG2E;
  int j0 = rowp[node];
  int j1 = rowp[node + 1];

  float den = 0.f;
  float a0 = 0.f, a1 = 0.f, a2 = 0.f, a3 = 0.f;
  const char* xlb8 = (const char*)xlb;
  const int goff = il << 3;               // 8B per lane within row

  // prologue: first chunk's colsrc (clamped within [j0, j1))
  int s0 = 0, s1 = 0, s2 = 0, s3 = 0;
  if (j0 < j1) {
    s0 = colsrc[j0];
    s1 = colsrc[(j0 + 1 < j1) ? j0 + 1 : j0];
    s2 = colsrc[(j0 + 2 < j1) ? j0 + 2 : j0];
    s3 = colsrc[(j0 + 3 < j1) ? j0 + 3 : j0];
  }

  for (int j = j0; j < j1; j += 4) {
    bool v1 = (j + 1) < j1, v2 = (j + 2) < j1, v3 = (j + 3) < j1;
    // gathers issue immediately (indices already resident)
    ushort4 g0 = *(const ushort4*)(xlb8 + (size_t)(unsigned)(s0 + goff));
    ushort4 g1 = *(const ushort4*)(xlb8 + (size_t)(unsigned)(s1 + goff));
    ushort4 g2 = *(const ushort4*)(xlb8 + (size_t)(unsigned)(s2 + goff));
    ushort4 g3 = *(const ushort4*)(xlb8 + (size_t)(unsigned)(s3 + goff));
    // prefetch next chunk's indices under this chunk's math
    int jn = j + 4;
    int t0i = colsrc[(jn < j1) ? jn : j];
    int t1i = colsrc[(jn + 1 < j1) ? jn + 1 : j];
    int t2i = colsrc[(jn + 2 < j1) ? jn + 2 : j];
    int t3i = colsrc[(jn + 3 < j1) ? jn + 3 : j];

    float x00 = bff(g0.x), x01 = bff(g0.y), x02 = bff(g0.z), x03 = bff(g0.w);
    float x10 = bff(g1.x), x11 = bff(g1.y), x12 = bff(g1.z), x13 = bff(g1.w);
    float x20 = bff(g2.x), x21 = bff(g2.y), x22 = bff(g2.z), x23 = bff(g2.w);
    float x30 = bff(g3.x), x31 = bff(g3.y), x32 = bff(g3.z), x33 = bff(g3.w);

    float t0, t1, t2, t3;
    t0 = x00 + xrv.x; t1 = x01 + xrv.y; t2 = x02 + xrv.z; t3 = x03 + xrv.w;
    t0 = fmaxf(t0, 0.2f * t0); t1 = fmaxf(t1, 0.2f * t1);
    t2 = fmaxf(t2, 0.2f * t2); t3 = fmaxf(t3, 0.2f * t3);
    float p0 = (t0 * atv.x + t1 * atv.y) + (t2 * atv.z + t3 * atv.w);
    t0 = x10 + xrv.x; t1 = x11 + xrv.y; t2 = x12 + xrv.z; t3 = x13 + xrv.w;
    t0 = fmaxf(t0, 0.2f * t0); t1 = fmaxf(t1, 0.2f * t1);
    t2 = fmaxf(t2, 0.2f * t2); t3 = fmaxf(t3, 0.2f * t3);
    float p1 = (t0 * atv.x + t1 * atv.y) + (t2 * atv.z + t3 * atv.w);
    t0 = x20 + xrv.x; t1 = x21 + xrv.y; t2 = x22 + xrv.z; t3 = x23 + xrv.w;
    t0 = fmaxf(t0, 0.2f * t0); t1 = fmaxf(t1, 0.2f * t1);
    t2 = fmaxf(t2, 0.2f * t2); t3 = fmaxf(t3, 0.2f * t3);
    float p2 = (t0 * atv.x + t1 * atv.y) + (t2 * atv.z + t3 * atv.w);
    t0 = x30 + xrv.x; t1 = x31 + xrv.y; t2 = x32 + xrv.z; t3 = x33 + xrv.w;
    t0 = fmaxf(t0, 0.2f * t0); t1 = fmaxf(t1, 0.2f * t1);
    t2 = fmaxf(t2, 0.2f * t2); t3 = fmaxf(t3, 0.2f * t3);
    float p3 = (t0 * atv.x + t1 * atv.y) + (t2 * atv.z + t3 * atv.w);

    // 8-lane (per-head) reduces — 4 independent chains pipeline in the VALU
    p0 = dpp_add<0xB1>(p0);  p1 = dpp_add<0xB1>(p1);
    p2 = dpp_add<0xB1>(p2);  p3 = dpp_add<0xB1>(p3);
    p0 = dpp_add<0x4E>(p0);  p1 = dpp_add<0x4E>(p1);
    p2 = dpp_add<0x4E>(p2);  p3 = dpp_add<0x4E>(p3);
    p0 = dpp_add<0x141>(p0); p1 = dpp_add<0x141>(p1);
    p2 = dpp_add<0x141>(p2); p3 = dpp_add<0x141>(p3);

    float w0 = exp2f(p0);
    float w1 = v1 ? exp2f(p1) : 0.f;
    float w2 = v2 ? exp2f(p2) : 0.f;
    float w3 = v3 ? exp2f(p3) : 0.f;
    den += (w0 + w1) + (w2 + w3);
    a0 += (w0 * x00 + w1 * x10) + (w2 * x20 + w3 * x30);
    a1 += (w0 * x01 + w1 * x11) + (w2 * x21 + w3 * x31);
    a2 += (w0 * x02 + w1 * x12) + (w2 * x22 + w3 * x32);
    a3 += (w0 * x03 + w1 * x13) + (w2 * x23 + w3 * x33);

    s0 = t0i; s1 = t1i; s2 = t2i; s3 = t3i;
  }

  float inv = 1.f / (den + 1e-16f);
  float4 bi = *(const float4*)(bias + d0);
  float vx0 = a0 * inv + bi.x, vx1 = a1 * inv + bi.y;
  float vx2 = a2 * inv + bi.z, vx3 = a3 * inv + bi.w;

  // LayerNorm over 128 dims within the 32-lane half
  float s1f = (vx0 + vx1) + (vx2 + vx3);
  float s2f = (vx0 * vx0 + vx1 * vx1) + (vx2 * vx2 + vx3 * vx3);
  s1f = dpp_add<0xB1>(s1f);  s2f = dpp_add<0xB1>(s2f);
  s1f = dpp_add<0x4E>(s1f);  s2f = dpp_add<0x4E>(s2f);
  s1f = dpp_add<0x124>(s1f); s2f = dpp_add<0x124>(s2f);
  s1f = dpp_add<0x128>(s1f); s2f = dpp_add<0x128>(s2f);
  s1f += __shfl_xor(s1f, 16); s2f += __shfl_xor(s2f, 16);
  float mean = s1f * (1.f / 128.f);
  float var = s2f * (1.f / 128.f) - mean * mean;
  float rstd = rsqrtf(var + 1e-5f);
  float4 gm = *(const float4*)(gam + d0);
  float4 bt = *(const float4*)(bet + d0);
  float n0 = (vx0 - mean) * rstd * gm.x + bt.x;
  float n1 = (vx1 - mean) * rstd * gm.y + bt.y;
  float n2 = (vx2 - mean) * rstd * gm.z + bt.z;
  float n3 = (vx3 - mean) * rstd * gm.w + bt.w;
  n0 = n0 > 0.f ? n0 : expf(n0) - 1.f;
  n1 = n1 > 0.f ? n1 : expf(n1) - 1.f;
  n2 = n2 > 0.f ? n2 : expf(n2) - 1.f;
  n3 = n3 > 0.f ? n3 : expf(n3) - 1.f;

  if (SPLIT) {
    int rb = node >> 4, lr16 = node & 15;
    int kt = d0 >> 5;
    int g = (d0 & 15) >> 2;
    int e0 = ((d0 >> 4) & 1) << 2;
    size_t off = ((((size_t)(rb * 4 + kt)) * 4 + g) * 16 + lr16) * 8 + e0;
    unsigned short h0 = bfh(n0), h1 = bfh(n1), h2 = bfh(n2), h3 = bfh(n3);
    ushort4 hv; hv.x = h0; hv.y = h1; hv.z = h2; hv.w = h3;
    ushort4 mv;
    mv.x = bfh(n0 - bff(h0)); mv.y = bfh(n1 - bff(h1));
    mv.z = bfh(n2 - bff(h2)); mv.w = bfh(n3 - bff(h3));
    *(ushort4*)(Oh + off) = hv;
    *(ushort4*)(Om + off) = mv;
  } else {
    float4 o; o.x = n0; o.y = n1; o.z = n2; o.w = n3;
    *(float4*)(out + (size_t)node * DD + d0) = o;
  }
}

extern "C" void kernel_launch(void* const* d_in, const int* in_sizes, int n_in,
                              void* d_out, int out_size, void* d_ws, size_t ws_size,
                              hipStream_t stream) {
  const float* x  = (const float*)d_in[0];
  const int*   ei = (const int*)d_in[1];
  const float* Wl[2]   = {(const float*)d_in[2],  (const float*)d_in[10]};
  const float* bl[2]   = {(const float*)d_in[3],  (const float*)d_in[11]};
  const float* Wr[2]   = {(const float*)d_in[4],  (const float*)d_in[12]};
  const float* br[2]   = {(const float*)d_in[5],  (const float*)d_in[13]};
  const float* att[2]  = {(const float*)d_in[6],  (const float*)d_in[14]};
  const float* bias[2] = {(const float*)d_in[7],  (const float*)d_in[15]};
  const float* gam[2]  = {(const float*)d_in[8],  (const float*)d_in[16]};
  const float* bet[2]  = {(const float*)d_in[9],  (const float*)d_in[17]};
  float* out = (float*)d_out;

  char* w = (char*)d_ws;
  auto carve = [&](size_t bytes) {
    char* p = w;
    w += (bytes + 255) & ~(size_t)255;
    return p;
  };
  unsigned short* xlb = (unsigned short*)carve((size_t)NN_PAD * DD * 2);
  unsigned short* xrb = (unsigned short*)carve((size_t)NN_PAD * DD * 2);
  int*   deg    = (int*)carve((size_t)NN * 4);
  int*   cur    = (int*)carve((size_t)NN * 4);
  int*   rowp   = (int*)carve((size_t)(NN + 1) * 4);
  int*   colsrc = (int*)carve((size_t)NE * 4);
  int*   bsum   = (int*)carve((size_t)SCAN_B * 4);
  unsigned short* Ah = (unsigned short*)carve((size_t)RB_PAD * 2048 * 2);
  unsigned short* Am = (unsigned short*)carve((size_t)RB_PAD * 2048 * 2);
  unsigned short* Bh = (unsigned short*)carve((size_t)8192 * 8 * 2);
  unsigned short* Bm = (unsigned short*)carve((size_t)8192 * 8 * 2);

  // D1: prep (A + both W) ∥ zero(deg)
  init_fused<<<RB_CNT + 32 + ZERO_BLKS, 256, 0, stream>>>(
      x, Wl[0], Wr[0], Wl[1], Wr[1], Ah, Am, Bh, Bm, deg);
  // D2: GEMM layer 0 ∥ count_deg
  count_gemm_fused<<<GEMM_BLKS + COUNT_BLKS, 256, 0, stream>>>(
      Ah, Am, Bh, Bm, bl[0], br[0], xlb, xrb, ei, deg);
  // D3-D5: CSR finalize
  scan_partial<<<SCAN_B, SCAN_T, 0, stream>>>(deg, rowp, bsum);
  scan_finish<<<SCAN_B, SCAN_T, 0, stream>>>(bsum, rowp, cur);
  scatter_src<<<COUNT_BLKS, 256, 0, stream>>>(ei, cur, colsrc);
  // D6: edge layer 0 (emits layer-1 A fragments)
  fused_edge_agg<1><<<(NN * 32 + 255) / 256, 256, 0, stream>>>(
      rowp, colsrc, xlb, xrb, att[0], bias[0], gam[0], bet[0], out, Ah, Am);
  // D7: GEMM layer 1
  dual_gemm_mfma<<<GEMM_BLKS, 256, 0, stream>>>(
      Ah, Am, Bh + (size_t)4096 * 8, Bm + (size_t)4096 * 8,
      bl[1], br[1], xlb, xrb);
  // D8: edge layer 1 (writes output)
  fused_edge_agg<0><<<(NN * 32 + 255) / 256, 256, 0, stream>>>(
      rowp, colsrc, xlb, xrb, att[1], bias[1], gam[1], bet[1], out, Ah, Am);
}

// Round 19
// 176.048 us; speedup vs baseline: 1.1036x; 1.0445x over previous
//
#include <hip/hip_runtime.h>

#define NN 50000
#define NN_PAD 50016  // grid-covered row pad (guard-free GEMM stores)
#define NE 600000
#define DD 128
#define NH 4
#define RB_CNT 3125   // NN/16 (exact)
#define RB_PAD 3128
#define GEMM_BLKS ((NN + 31) / 32)          // 1563
#define COUNT_BLKS ((NE + 255) / 256)       // 2344
#define ZERO_BLKS ((NN / 4 + 255) / 256)    // 49

#define SCAN_T 512
#define SCAN_B ((NN + SCAN_T - 1) / SCAN_T)

#define LOG2E 1.44269504088896340736f

typedef short s16x8 __attribute__((ext_vector_type(8)));
typedef float f32x4 __attribute__((ext_vector_type(4)));

// fp32 -> bf16 (RNE) and back
__device__ __forceinline__ unsigned short bfh(float f) {
  unsigned u = __float_as_uint(f);
  return (unsigned short)((u + 0x7fffu + ((u >> 16) & 1u)) >> 16);
}
__device__ __forceinline__ float bff(unsigned short h) {
  return __uint_as_float(((unsigned)h) << 16);
}

// cross-lane add via DPP. 0xB1 quad xor1, 0x4E quad xor2, 0x141 row_half_mirror,
// 0x124/0x128 row_ror:4/:8.
template <int CTRL>
__device__ __forceinline__ float dpp_add(float x) {
  int y = __builtin_amdgcn_update_dpp(0, __float_as_int(x), CTRL, 0xf, 0xf, true);
  return x + __int_as_float(y);
}

// ---------- device bodies (shared by fused dispatches) ----------
__device__ __forceinline__ void prep_a_body(
    int tid, const float* __restrict__ h,
    unsigned short* __restrict__ Ah, unsigned short* __restrict__ Am) {
  int lr = tid & 15;
  int g = (tid >> 4) & 3;
  int kt = (tid >> 6) & 3;
  int rb = tid >> 8;
  int row = rb * 16 + lr;
  const float* p = h + (size_t)row * DD + kt * 32 + 4 * g;
  float4 f0 = *(const float4*)(p);
  float4 f1 = *(const float4*)(p + 16);
  float fs[8] = {f0.x, f0.y, f0.z, f0.w, f1.x, f1.y, f1.z, f1.w};
  s16x8 hi, mid;
#pragma unroll
  for (int e = 0; e < 8; e++) {
    unsigned short hh = bfh(fs[e]);
    hi[e] = (short)hh;
    mid[e] = (short)bfh(fs[e] - bff(hh));
  }
  *(s16x8*)(Ah + (size_t)tid * 8) = hi;
  *(s16x8*)(Am + (size_t)tid * 8) = mid;
}

__device__ __forceinline__ void prep_w_body(
    int tid, const float* __restrict__ Wl0, const float* __restrict__ Wr0,
    const float* __restrict__ Wl1, const float* __restrict__ Wr1,
    unsigned short* __restrict__ Bh, unsigned short* __restrict__ Bm) {
  int lay = tid >> 12;
  int t = tid & 4095;
  int lr = t & 15;
  int g = (t >> 4) & 3;
  int kt = (t >> 6) & 3;
  int ct = t >> 8;
  int col = ct * 16 + lr;
  const float* W = (col < DD) ? (lay ? Wl1 : Wl0) : (lay ? Wr1 : Wr0);
  int cc = (col < DD) ? col : col - DD;
  s16x8 hi, mid;
#pragma unroll
  for (int e = 0; e < 8; e++) {
    int k = kt * 32 + ((e >> 2) << 4) + 4 * g + (e & 3);
    float w = W[(size_t)k * DD + cc];
    unsigned short hh = bfh(w);
    hi[e] = (short)hh;
    mid[e] = (short)bfh(w - bff(hh));
  }
  *(s16x8*)(Bh + (size_t)tid * 8) = hi;
  *(s16x8*)(Bm + (size_t)tid * 8) = mid;
}

__device__ __forceinline__ void gemm_body(
    int bid, int tid,
    const unsigned short* __restrict__ Ah, const unsigned short* __restrict__ Am,
    const unsigned short* __restrict__ Bh, const unsigned short* __restrict__ Bm,
    const float* __restrict__ blv, const float* __restrict__ brv,
    unsigned short* __restrict__ xlb, unsigned short* __restrict__ xrb) {
  const int lane = tid & 63;
  const int wv = tid >> 6;
  const int lr = lane & 15;
  const int g = lane >> 4;
  const int rb0 = bid * 2;

  f32x4 acc[2][4];
#pragma unroll
  for (int rt = 0; rt < 2; rt++)
#pragma unroll
    for (int nt = 0; nt < 4; nt++)
#pragma unroll
      for (int e = 0; e < 4; e++) acc[rt][nt][e] = 0.f;

#pragma unroll
  for (int kt = 0; kt < 4; kt++) {
    s16x8 ah[2], am[2], bh[4], bm[4];
#pragma unroll
    for (int rt = 0; rt < 2; rt++) {
      size_t off = ((((size_t)((rb0 + rt) * 4 + kt)) * 4 + g) * 16 + lr) * 8;
      ah[rt] = *(const s16x8*)(Ah + off);
      am[rt] = *(const s16x8*)(Am + off);
    }
#pragma unroll
    for (int nt = 0; nt < 4; nt++) {
      int ct = wv * 4 + nt;
      size_t off = ((((size_t)(ct * 4 + kt)) * 4 + g) * 16 + lr) * 8;
      bh[nt] = *(const s16x8*)(Bh + off);
      bm[nt] = *(const s16x8*)(Bm + off);
    }
#pragma unroll
    for (int rt = 0; rt < 2; rt++)
#pragma unroll
      for (int nt = 0; nt < 4; nt++) {
        acc[rt][nt] = __builtin_amdgcn_mfma_f32_16x16x32_bf16(ah[rt], bh[nt], acc[rt][nt], 0, 0, 0);
        acc[rt][nt] = __builtin_amdgcn_mfma_f32_16x16x32_bf16(ah[rt], bm[nt], acc[rt][nt], 0, 0, 0);
        acc[rt][nt] = __builtin_amdgcn_mfma_f32_16x16x32_bf16(am[rt], bh[nt], acc[rt][nt], 0, 0, 0);
      }
  }

#pragma unroll
  for (int nt = 0; nt < 4; nt++) {
    int col = wv * 64 + nt * 16 + lr;
    unsigned short* dst = (col < DD) ? (xlb + col) : (xrb + (col - DD));
    float bv = (col < DD) ? blv[col] : brv[col - DD];
#pragma unroll
    for (int rt = 0; rt < 2; rt++) {
      int rowb = bid * 32 + rt * 16 + 4 * g;
#pragma unroll
      for (int r = 0; r < 4; r++)
        dst[(size_t)(rowb + r) * DD] = bfh(acc[rt][nt][r] + bv);   // rows < NN_PAD
    }
  }
}

// ---------- dispatch 1: prep_all ∥ zero_deg ∥ colsrc pad ----------
__global__ __launch_bounds__(256) void init_fused(
    const float* __restrict__ h,
    const float* __restrict__ Wl0, const float* __restrict__ Wr0,
    const float* __restrict__ Wl1, const float* __restrict__ Wr1,
    unsigned short* __restrict__ Ah, unsigned short* __restrict__ Am,
    unsigned short* __restrict__ Bh, unsigned short* __restrict__ Bm,
    int* __restrict__ deg, int* __restrict__ colsrc) {
  int b = blockIdx.x;
  if (b < RB_CNT) {
    prep_a_body(b * 256 + threadIdx.x, h, Ah, Am);
  } else if (b < RB_CNT + 32) {
    prep_w_body((b - RB_CNT) * 256 + threadIdx.x, Wl0, Wr0, Wl1, Wr1, Bh, Bm);
  } else {
    int i = ((b - RB_CNT - 32) * 256 + threadIdx.x) << 2;
    if (i < NN) {
      if (i + 3 < NN) *(int4*)(deg + i) = make_int4(0, 0, 0, 0);
      else for (int k = i; k < NN; k++) deg[k] = 0;
    }
    if (b == RB_CNT + 32 && threadIdx.x < 16) colsrc[NE + threadIdx.x] = 0;  // pad
  }
}

// ---------- dispatch 2: GEMM layer 0 ∥ count_deg ----------
__global__ __launch_bounds__(256, 3) void count_gemm_fused(
    const unsigned short* __restrict__ Ah, const unsigned short* __restrict__ Am,
    const unsigned short* __restrict__ Bh, const unsigned short* __restrict__ Bm,
    const float* __restrict__ blv, const float* __restrict__ brv,
    unsigned short* __restrict__ xlb, unsigned short* __restrict__ xrb,
    const int* __restrict__ ei, int* __restrict__ deg) {
  int b = blockIdx.x;
  if (b < GEMM_BLKS) {
    gemm_body(b, threadIdx.x, Ah, Am, Bh, Bm, blv, brv, xlb, xrb);
  } else {
    int e = (b - GEMM_BLKS) * 256 + threadIdx.x;
    if (e < NE) atomicAdd(deg + ei[NE + e], 1);
  }
}

// ---------- plain GEMM (layer 1) ----------
__global__ __launch_bounds__(256, 3) void dual_gemm_mfma(
    const unsigned short* __restrict__ Ah, const unsigned short* __restrict__ Am,
    const unsigned short* __restrict__ Bh, const unsigned short* __restrict__ Bm,
    const float* __restrict__ blv, const float* __restrict__ brv,
    unsigned short* __restrict__ xlb, unsigned short* __restrict__ xrb) {
  gemm_body(blockIdx.x, threadIdx.x, Ah, Am, Bh, Bm, blv, brv, xlb, xrb);
}

// ---------- CSR scans ----------
__global__ __launch_bounds__(SCAN_T) void scan_partial(
    const int* __restrict__ deg, int* __restrict__ rowp, int* __restrict__ bsum) {
  __shared__ int buf[SCAN_T];
  int b = blockIdx.x, t = threadIdx.x;
  int i = b * SCAN_T + t;
  int v = (i < NN) ? deg[i] : 0;
  buf[t] = v;
  __syncthreads();
  for (int o = 1; o < SCAN_T; o <<= 1) {
    int add = (t >= o) ? buf[t - o] : 0;
    __syncthreads();
    buf[t] += add;
    __syncthreads();
  }
  if (i < NN) rowp[i] = buf[t] - v;
  if (t == SCAN_T - 1) bsum[b] = buf[t];
}

__global__ __launch_bounds__(SCAN_T) void scan_finish(
    const int* __restrict__ bsum, int* __restrict__ rowp, int* __restrict__ cur) {
  __shared__ int sb[SCAN_T];
  int b = blockIdx.x, t = threadIdx.x;
  int v = (t < SCAN_B) ? bsum[t] : 0;
  sb[t] = v;
  __syncthreads();
  for (int o = 1; o < SCAN_T; o <<= 1) {
    int add = (t >= o) ? sb[t - o] : 0;
    __syncthreads();
    sb[t] += add;
    __syncthreads();
  }
  int boff = sb[b] - bsum[b];
  int i = b * SCAN_T + t;
  if (i < NN) {
    int r = rowp[i] + boff;
    rowp[i] = r;
    cur[i] = r;
  }
  if (b == 0 && t == 0) rowp[NN] = sb[SCAN_B - 1];
}

__global__ void scatter_src(const int* __restrict__ ei,
                            int* __restrict__ cur, int* __restrict__ colsrc) {
  int e = blockIdx.x * 256 + threadIdx.x;
  if (e < NE) {
    int d = ei[NE + e];
    int p = atomicAdd(cur + d, 1);
    colsrc[p] = ei[e] << 8;
  }
}

// ---------- fused edge path v8: half-wave per node, 4-edge chunks,
//            2-deep software pipeline (gathers AND indices in flight) ----------
template <int SPLIT>
__global__ __launch_bounds__(256) void fused_edge_agg(
    const int* __restrict__ rowp, const int* __restrict__ colsrc,
    const unsigned short* __restrict__ xlb, const unsigned short* __restrict__ xrb,
    const float* __restrict__ att, const float* __restrict__ bias,
    const float* __restrict__ gam, const float* __restrict__ bet,
    float* __restrict__ out, unsigned short* __restrict__ Oh,
    unsigned short* __restrict__ Om) {
  int node = (blockIdx.x * 256 + threadIdx.x) >> 5;   // half-wave id
  if (node >= NN) return;
  int il = threadIdx.x & 31;
  int d0 = il << 2;                       // 4 dims per lane; head = il>>3

  ushort4 xru = *(const ushort4*)(xrb + (size_t)node * DD + d0);
  float4 xrv; xrv.x = bff(xru.x); xrv.y = bff(xru.y);
  xrv.z = bff(xru.z); xrv.w = bff(xru.w);
  float4 atv = *(const float4*)(att + d0);
  atv.x *= LOG2E; atv.y *= LOG2E; atv.z *= LOG2E; atv.w *= LOG2E;
  int j0 = rowp[node];
  int j1 = rowp[node + 1];

  float den = 0.f;
  float a0 = 0.f, a1 = 0.f, a2 = 0.f, a3 = 0.f;
  const char* xlb8 = (const char*)xlb;
  const int goff = il << 3;               // 8B per lane within row

  // prologue (colsrc padded by 16 zeros past NE — all loads unconditional)
  ushort4 gA0, gA1, gA2, gA3;
  int sB0 = 0, sB1 = 0, sB2 = 0, sB3 = 0;
  if (j0 < j1) {
    int sA0 = colsrc[j0], sA1 = colsrc[j0 + 1];
    int sA2 = colsrc[j0 + 2], sA3 = colsrc[j0 + 3];
    gA0 = *(const ushort4*)(xlb8 + (size_t)(unsigned)(sA0 + goff));
    gA1 = *(const ushort4*)(xlb8 + (size_t)(unsigned)(sA1 + goff));
    gA2 = *(const ushort4*)(xlb8 + (size_t)(unsigned)(sA2 + goff));
    gA3 = *(const ushort4*)(xlb8 + (size_t)(unsigned)(sA3 + goff));
    sB0 = colsrc[j0 + 4]; sB1 = colsrc[j0 + 5];
    sB2 = colsrc[j0 + 6]; sB3 = colsrc[j0 + 7];
  }

  for (int j = j0; j < j1; j += 4) {
    // issue next chunk's gathers (indices already resident)
    ushort4 gB0 = *(const ushort4*)(xlb8 + (size_t)(unsigned)(sB0 + goff));
    ushort4 gB1 = *(const ushort4*)(xlb8 + (size_t)(unsigned)(sB1 + goff));
    ushort4 gB2 = *(const ushort4*)(xlb8 + (size_t)(unsigned)(sB2 + goff));
    ushort4 gB3 = *(const ushort4*)(xlb8 + (size_t)(unsigned)(sB3 + goff));
    // issue next-next chunk's indices
    int sC0 = colsrc[j + 8],  sC1 = colsrc[j + 9];
    int sC2 = colsrc[j + 10], sC3 = colsrc[j + 11];

    bool v1 = (j + 1) < j1, v2 = (j + 2) < j1, v3 = (j + 3) < j1;
    float x00 = bff(gA0.x), x01 = bff(gA0.y), x02 = bff(gA0.z), x03 = bff(gA0.w);
    float x10 = bff(gA1.x), x11 = bff(gA1.y), x12 = bff(gA1.z), x13 = bff(gA1.w);
    float x20 = bff(gA2.x), x21 = bff(gA2.y), x22 = bff(gA2.z), x23 = bff(gA2.w);
    float x30 = bff(gA3.x), x31 = bff(gA3.y), x32 = bff(gA3.z), x33 = bff(gA3.w);

    float t0, t1, t2, t3;
    t0 = x00 + xrv.x; t1 = x01 + xrv.y; t2 = x02 + xrv.z; t3 = x03 + xrv.w;
    t0 = fmaxf(t0, 0.2f * t0); t1 = fmaxf(t1, 0.2f * t1);
    t2 = fmaxf(t2, 0.2f * t2); t3 = fmaxf(t3, 0.2f * t3);
    float p0 = (t0 * atv.x + t1 * atv.y) + (t2 * atv.z + t3 * atv.w);
    t0 = x10 + xrv.x; t1 = x11 + xrv.y; t2 = x12 + xrv.z; t3 = x13 + xrv.w;
    t0 = fmaxf(t0, 0.2f * t0); t1 = fmaxf(t1, 0.2f * t1);
    t2 = fmaxf(t2, 0.2f * t2); t3 = fmaxf(t3, 0.2f * t3);
    float p1 = (t0 * atv.x + t1 * atv.y) + (t2 * atv.z + t3 * atv.w);
    t0 = x20 + xrv.x; t1 = x21 + xrv.y; t2 = x22 + xrv.z; t3 = x23 + xrv.w;
    t0 = fmaxf(t0, 0.2f * t0); t1 = fmaxf(t1, 0.2f * t1);
    t2 = fmaxf(t2, 0.2f * t2); t3 = fmaxf(t3, 0.2f * t3);
    float p2 = (t0 * atv.x + t1 * atv.y) + (t2 * atv.z + t3 * atv.w);
    t0 = x30 + xrv.x; t1 = x31 + xrv.y; t2 = x32 + xrv.z; t3 = x33 + xrv.w;
    t0 = fmaxf(t0, 0.2f * t0); t1 = fmaxf(t1, 0.2f * t1);
    t2 = fmaxf(t2, 0.2f * t2); t3 = fmaxf(t3, 0.2f * t3);
    float p3 = (t0 * atv.x + t1 * atv.y) + (t2 * atv.z + t3 * atv.w);

    p0 = dpp_add<0xB1>(p0);  p1 = dpp_add<0xB1>(p1);
    p2 = dpp_add<0xB1>(p2);  p3 = dpp_add<0xB1>(p3);
    p0 = dpp_add<0x4E>(p0);  p1 = dpp_add<0x4E>(p1);
    p2 = dpp_add<0x4E>(p2);  p3 = dpp_add<0x4E>(p3);
    p0 = dpp_add<0x141>(p0); p1 = dpp_add<0x141>(p1);
    p2 = dpp_add<0x141>(p2); p3 = dpp_add<0x141>(p3);

    float w0 = exp2f(p0);
    float w1 = v1 ? exp2f(p1) : 0.f;
    float w2 = v2 ? exp2f(p2) : 0.f;
    float w3 = v3 ? exp2f(p3) : 0.f;
    den += (w0 + w1) + (w2 + w3);
    a0 += (w0 * x00 + w1 * x10) + (w2 * x20 + w3 * x30);
    a1 += (w0 * x01 + w1 * x11) + (w2 * x21 + w3 * x31);
    a2 += (w0 * x02 + w1 * x12) + (w2 * x22 + w3 * x32);
    a3 += (w0 * x03 + w1 * x13) + (w2 * x23 + w3 * x33);

    gA0 = gB0; gA1 = gB1; gA2 = gB2; gA3 = gB3;
    sB0 = sC0; sB1 = sC1; sB2 = sC2; sB3 = sC3;
  }

  float inv = 1.f / (den + 1e-16f);
  float4 bi = *(const float4*)(bias + d0);
  float vx0 = a0 * inv + bi.x, vx1 = a1 * inv + bi.y;
  float vx2 = a2 * inv + bi.z, vx3 = a3 * inv + bi.w;

  // LayerNorm over 128 dims within the 32-lane half
  float s1f = (vx0 + vx1) + (vx2 + vx3);
  float s2f = (vx0 * vx0 + vx1 * vx1) + (vx2 * vx2 + vx3 * vx3);
  s1f = dpp_add<0xB1>(s1f);  s2f = dpp_add<0xB1>(s2f);
  s1f = dpp_add<0x4E>(s1f);  s2f = dpp_add<0x4E>(s2f);
  s1f = dpp_add<0x124>(s1f); s2f = dpp_add<0x124>(s2f);
  s1f = dpp_add<0x128>(s1f); s2f = dpp_add<0x128>(s2f);
  s1f += __shfl_xor(s1f, 16); s2f += __shfl_xor(s2f, 16);
  float mean = s1f * (1.f / 128.f);
  float var = s2f * (1.f / 128.f) - mean * mean;
  float rstd = rsqrtf(var + 1e-5f);
  float4 gm = *(const float4*)(gam + d0);
  float4 bt = *(const float4*)(bet + d0);
  float n0 = (vx0 - mean) * rstd * gm.x + bt.x;
  float n1 = (vx1 - mean) * rstd * gm.y + bt.y;
  float n2 = (vx2 - mean) * rstd * gm.z + bt.z;
  float n3 = (vx3 - mean) * rstd * gm.w + bt.w;
  n0 = n0 > 0.f ? n0 : __expf(n0) - 1.f;
  n1 = n1 > 0.f ? n1 : __expf(n1) - 1.f;
  n2 = n2 > 0.f ? n2 : __expf(n2) - 1.f;
  n3 = n3 > 0.f ? n3 : __expf(n3) - 1.f;

  if (SPLIT) {
    int rb = node >> 4, lr16 = node & 15;
    int kt = d0 >> 5;
    int g = (d0 & 15) >> 2;
    int e0 = ((d0 >> 4) & 1) << 2;
    size_t off = ((((size_t)(rb * 4 + kt)) * 4 + g) * 16 + lr16) * 8 + e0;
    unsigned short h0 = bfh(n0), h1 = bfh(n1), h2 = bfh(n2), h3 = bfh(n3);
    ushort4 hv; hv.x = h0; hv.y = h1; hv.z = h2; hv.w = h3;
    ushort4 mv;
    mv.x = bfh(n0 - bff(h0)); mv.y = bfh(n1 - bff(h1));
    mv.z = bfh(n2 - bff(h2)); mv.w = bfh(n3 - bff(h3));
    *(ushort4*)(Oh + off) = hv;
    *(ushort4*)(Om + off) = mv;
  } else {
    float4 o; o.x = n0; o.y = n1; o.z = n2; o.w = n3;
    *(float4*)(out + (size_t)node * DD + d0) = o;
  }
}

extern "C" void kernel_launch(void* const* d_in, const int* in_sizes, int n_in,
                              void* d_out, int out_size, void* d_ws, size_t ws_size,
                              hipStream_t stream) {
  const float* x  = (const float*)d_in[0];
  const int*   ei = (const int*)d_in[1];
  const float* Wl[2]   = {(const float*)d_in[2],  (const float*)d_in[10]};
  const float* bl[2]   = {(const float*)d_in[3],  (const float*)d_in[11]};
  const float* Wr[2]   = {(const float*)d_in[4],  (const float*)d_in[12]};
  const float* br[2]   = {(const float*)d_in[5],  (const float*)d_in[13]};
  const float* att[2]  = {(const float*)d_in[6],  (const float*)d_in[14]};
  const float* bias[2] = {(const float*)d_in[7],  (const float*)d_in[15]};
  const float* gam[2]  = {(const float*)d_in[8],  (const float*)d_in[16]};
  const float* bet[2]  = {(const float*)d_in[9],  (const float*)d_in[17]};
  float* out = (float*)d_out;

  char* w = (char*)d_ws;
  auto carve = [&](size_t bytes) {
    char* p = w;
    w += (bytes + 255) & ~(size_t)255;
    return p;
  };
  unsigned short* xlb = (unsigned short*)carve((size_t)NN_PAD * DD * 2);
  unsigned short* xrb = (unsigned short*)carve((size_t)NN_PAD * DD * 2);
  int*   deg    = (int*)carve((size_t)NN * 4);
  int*   cur    = (int*)carve((size_t)NN * 4);
  int*   rowp   = (int*)carve((size_t)(NN + 1) * 4);
  int*   colsrc = (int*)carve((size_t)(NE + 16) * 4);
  int*   bsum   = (int*)carve((size_t)SCAN_B * 4);
  unsigned short* Ah = (unsigned short*)carve((size_t)RB_PAD * 2048 * 2);
  unsigned short* Am = (unsigned short*)carve((size_t)RB_PAD * 2048 * 2);
  unsigned short* Bh = (unsigned short*)carve((size_t)8192 * 8 * 2);
  unsigned short* Bm = (unsigned short*)carve((size_t)8192 * 8 * 2);

  // D1: prep (A + both W) ∥ zero(deg) ∥ colsrc pad
  init_fused<<<RB_CNT + 32 + ZERO_BLKS, 256, 0, stream>>>(
      x, Wl[0], Wr[0], Wl[1], Wr[1], Ah, Am, Bh, Bm, deg, colsrc);
  // D2: GEMM layer 0 ∥ count_deg
  count_gemm_fused<<<GEMM_BLKS + COUNT_BLKS, 256, 0, stream>>>(
      Ah, Am, Bh, Bm, bl[0], br[0], xlb, xrb, ei, deg);
  // D3-D5: CSR finalize
  scan_partial<<<SCAN_B, SCAN_T, 0, stream>>>(deg, rowp, bsum);
  scan_finish<<<SCAN_B, SCAN_T, 0, stream>>>(bsum, rowp, cur);
  scatter_src<<<COUNT_BLKS, 256, 0, stream>>>(ei, cur, colsrc);
  // D6: edge layer 0 (emits layer-1 A fragments)
  fused_edge_agg<1><<<(NN * 32 + 255) / 256, 256, 0, stream>>>(
      rowp, colsrc, xlb, xrb, att[0], bias[0], gam[0], bet[0], out, Ah, Am);
  // D7: GEMM layer 1
  dual_gemm_mfma<<<GEMM_BLKS, 256, 0, stream>>>(
      Ah, Am, Bh + (size_t)4096 * 8, Bm + (size_t)4096 * 8,
      bl[1], br[1], xlb, xrb);
  // D8: edge layer 1 (writes output)
  fused_edge_agg<0><<<(NN * 32 + 255) / 256, 256, 0, stream>>>(
      rowp, colsrc, xlb, xrb, att[1], bias[1], gam[1], bet[1], out, Ah, Am);
}